// Round 6
// baseline (310.195 us; speedup 1.0000x reference)
//
#include <hip/hip_runtime.h>

// Problem constants (fixed shapes from setup_inputs)
constexpr int B  = 4;
constexpr int N  = 16384;   // dense points
constexpr int S  = 4096;    // sparse points
constexpr int CD = 128;     // dense feature channels
constexpr int CS = 256;     // sparse feature channels
constexpr int CO = 128;     // output channels
constexpr int CIN = CD + CS; // 384

// KNN decomposition
constexpr int NC = 4;      // S-chunks
constexpr int CH = S / NC; // 1024 sparse points per chunk
constexpr int P  = 2;      // dense points per thread

// Insert x into ascending (k0,k1,k2), dropping the largest. 5 f64 min/max.
__device__ __forceinline__ void insert3(double& k0, double& k1, double& k2,
                                        double x) {
  const double m0 = fmax(k0, x);
  const double m1 = fmax(k1, x);
  k0 = fmin(k0, x);
  k1 = fmin(k1, m0);
  k2 = fmin(k2, m1);
}

// Packed key: f64(t_f32) with 12 index bits OR'd into the low mantissa.
// f32->f64 is exact (29 zero trailing mantissa bits), so ordering is exactly
// lexicographic (t, idx'). Doubles are sign-magnitude: for t<0 a larger
// mantissa is MORE negative, so pack (0xFFF^sg) there to keep
// lower-index-wins tie-breaking; un-flip at recovery.
__device__ __forceinline__ double pack_key(float t, unsigned sg) {
  const unsigned sga = (t < 0.f) ? (0xFFFu ^ sg) : sg;
  return __longlong_as_double(__double_as_longlong((double)t) |
                              (unsigned long long)sga);
}
__device__ __forceinline__ int unpack_idx(double k) {
  const long long bits = __double_as_longlong(k);
  const int low = (int)(bits & 0xFFFll);
  return (bits < 0) ? (0xFFF ^ low) : low;
}

// ---------------------------------------------------------------------------
// K1a: per-chunk top-3, two-pass.
// Pass 1 (every pair, f32-only): t = -2*d.s + s2 via 3 fma (premultiplied
// LDS tile), top-3 VALUES via 4-op min/med3/max network. 7 inst/pair.
// Pass 2: recompute bit-identical t; only candidates with t <= thr (3rd
// best) enter the rare exec-masked branch that does the exact f64-key
// insert. R5 paid ~66 cyc/pair for f64 everywhere; this pays ~30.
// ---------------------------------------------------------------------------
__global__ __launch_bounds__(256) void knn_chunk_kernel(
    const float* __restrict__ dxyz, const float* __restrict__ sxyz,
    double* __restrict__ ckey) {
  __shared__ float4 sp[CH];   // (-2sx, -2sy, -2sz, s2)
  const int b = blockIdx.z;
  const int c = blockIdx.y;
  const int nbase = blockIdx.x * (256 * P);
  const int t = threadIdx.x;

  const float* sb = sxyz + b * 3 * S + c * CH;
  for (int j = t; j < CH; j += 256) {
    const float sx = sb[j], sy = sb[S + j], sz = sb[2 * S + j];
    sp[j] = make_float4(-2.f * sx, -2.f * sy, -2.f * sz,
                        fmaf(sx, sx, fmaf(sy, sy, sz * sz)));
  }
  __syncthreads();

  float bx[P], by[P], bz[P];
  float d0[P], d1[P], d2[P];
  #pragma unroll
  for (int p = 0; p < P; ++p) {
    const int n = nbase + p * 256 + t;
    bx[p] = dxyz[b * 3 * N + n];
    by[p] = dxyz[b * 3 * N + N + n];
    bz[p] = dxyz[b * 3 * N + 2 * N + n];
    d0[p] = d1[p] = d2[p] = 1e30f;
  }

  // ---- pass 1: distances only ----
  #pragma unroll 4
  for (int j = 0; j < CH; ++j) {
    const float4 q = sp[j];   // wave-uniform LDS broadcast
    #pragma unroll
    for (int p = 0; p < P; ++p) {
      const float x = fmaf(q.x, bx[p], fmaf(q.y, by[p], fmaf(q.z, bz[p], q.w)));
      d2[p] = fminf(fmaxf(x, d1[p]), d2[p]);
      d1[p] = __builtin_amdgcn_fmed3f(x, d0[p], d1[p]);
      d0[p] = fminf(x, d0[p]);
    }
  }

  // ---- pass 2: index recovery for t <= thr (>=3 hits, ties included) ----
  double k0[P], k1[P], k2[P];
  #pragma unroll
  for (int p = 0; p < P; ++p) { k0[p] = k1[p] = k2[p] = 1e300; }

  #pragma unroll 2
  for (int j = 0; j < CH; ++j) {
    const float4 q = sp[j];
    const unsigned sg = (unsigned)(c * CH + j);  // global sparse index
    #pragma unroll
    for (int p = 0; p < P; ++p) {
      const float x = fmaf(q.x, bx[p], fmaf(q.y, by[p], fmaf(q.z, bz[p], q.w)));
      if (x <= d2[p]) {                       // rare exec-masked path
        insert3(k0[p], k1[p], k2[p], pack_key(x, sg));
      }
    }
  }

  #pragma unroll
  for (int p = 0; p < P; ++p) {
    const int n = nbase + p * 256 + t;
    const size_t base = (((size_t)c * B + b) * N + n) * 3;
    ckey[base + 0] = k0[p];
    ckey[base + 1] = k1[p];
    ckey[base + 2] = k2[p];
  }
}

// ---------------------------------------------------------------------------
// K1b: merge the NC per-chunk key triples, recover indices, and compute
// weights in the REFERENCE's expanded form max((n2+s2)-2*inner, 0).
// ---------------------------------------------------------------------------
__global__ __launch_bounds__(256) void knn_merge_kernel(
    const double* __restrict__ ckey, const float* __restrict__ dxyz,
    const float* __restrict__ sxyz, float* __restrict__ wgt,
    int* __restrict__ idx) {
  const int gid = blockIdx.x * 256 + threadIdx.x;  // = b*N + n
  const int b = gid >> 14;                          // N = 16384
  const int n = gid & (N - 1);
  double k0 = 1e300, k1 = 1e300, k2 = 1e300;
  #pragma unroll
  for (int c = 0; c < NC; ++c) {
    const size_t base = ((size_t)c * B * N + gid) * 3;
    insert3(k0, k1, k2, ckey[base + 0]);
    insert3(k0, k1, k2, ckey[base + 1]);
    insert3(k0, k1, k2, ckey[base + 2]);
  }
  int ii[3];
  ii[0] = unpack_idx(k0);
  ii[1] = unpack_idx(k1);
  ii[2] = unpack_idx(k2);

  const float bx = dxyz[b * 3 * N + n];
  const float by = dxyz[b * 3 * N + N + n];
  const float bz = dxyz[b * 3 * N + 2 * N + n];
  const float n2 = bx * bx + by * by + bz * bz;
  float w[3];
  #pragma unroll
  for (int k = 0; k < 3; ++k) {
    const float sx = sxyz[b * 3 * S + ii[k]];
    const float sy = sxyz[b * 3 * S + S + ii[k]];
    const float sz = sxyz[b * 3 * S + 2 * S + ii[k]];
    const float s2 = sx * sx + sy * sy + sz * sz;
    const float inner = bx * sx + by * sy + bz * sz;
    const float d = fmaxf((n2 + s2) - 2.f * inner, 0.f);
    w[k] = 1.f / (d + 1e-8f);
  }
  const float inv = 1.f / (w[0] + w[1] + w[2]);
  const size_t base = (size_t)gid * 3;
  wgt[base + 0] = w[0] * inv;
  wgt[base + 1] = w[1] * inv;
  wgt[base + 2] = w[2] * inv;
  idx[base + 0] = ii[0];
  idx[base + 1] = ii[1];
  idx[base + 2] = ii[2];
}

// ---------------------------------------------------------------------------
// K1c: transpose conv_w -> Wt[c][o] (o contiguous) for zproj's uniform loads.
// ---------------------------------------------------------------------------
__global__ __launch_bounds__(256) void wtrans_kernel(
    const float* __restrict__ cw, float* __restrict__ wt) {
  const int i = blockIdx.x * 256 + threadIdx.x;  // over CO*CIN, coalesced read
  const int o = i / CIN;
  const int c = i - o * CIN;
  wt[c * CO + o] = cw[i];
}

// ---------------------------------------------------------------------------
// K2: Z[b, s, o] = sum_c Ws[o, c] * sparse_data[b, c, s]   (o-contiguous!)
// 1-wave blocks, 16 channels/thread, grid (S/64, CO/16, B) = 2048 waves.
// ---------------------------------------------------------------------------
__global__ __launch_bounds__(64) void zproj_kernel(
    const float* __restrict__ sdata, const float* __restrict__ wt,
    float* __restrict__ Z) {
  const int b = blockIdx.z;
  const int og = blockIdx.y;                      // 8 groups of 16 channels
  const int s = blockIdx.x * 64 + threadIdx.x;
  const float* __restrict__ xp = sdata + b * CS * S + s;
  const float* __restrict__ wp = wt + CD * CO + og * 16;  // Wt[CD+c][og*16..]

  float acc[16];
  #pragma unroll
  for (int i = 0; i < 16; ++i) acc[i] = 0.f;

  #pragma unroll 4
  for (int c = 0; c < CS; ++c) {
    const float xv = xp[c * S];        // coalesced across the wave
    #pragma unroll
    for (int i = 0; i < 16; ++i)
      acc[i] = fmaf(wp[c * CO + i], xv, acc[i]);  // uniform 64B s_load
  }

  float4* zp = reinterpret_cast<float4*>(Z + (b * S + s) * CO + og * 16);
  #pragma unroll
  for (int i = 0; i < 4; ++i)
    zp[i] = make_float4(acc[4*i+0], acc[4*i+1], acc[4*i+2], acc[4*i+3]);
}

// ---------------------------------------------------------------------------
// K3: y[b, o, n] = sum_c Wd[o,c]*dense_data[b,c,n] + sum_k w_k * Z[b,idx_k,o]
// (no fused stats — R3 showed that fusion forces an accumulator spill)
// ---------------------------------------------------------------------------
__global__ __launch_bounds__(256) void ygemm_kernel(
    const float* __restrict__ ddata, const float* __restrict__ cw,
    const float* __restrict__ Z, const float* __restrict__ wgt,
    const int* __restrict__ idx, float* __restrict__ y) {
  const int b = blockIdx.y;
  const int n = blockIdx.x * 64 + (threadIdx.x & 63);
  const int rg = __builtin_amdgcn_readfirstlane(threadIdx.x >> 6);
  const float* __restrict__ xp = ddata + b * CD * N + n;
  const float* __restrict__ wp = cw + rg * 32 * CIN;  // Wd columns

  float acc[32];
  #pragma unroll
  for (int i = 0; i < 32; ++i) acc[i] = 0.f;

  #pragma unroll 4
  for (int c = 0; c < CD; ++c) {
    const float xv = xp[c * N];
    #pragma unroll
    for (int i = 0; i < 32; ++i)
      acc[i] = fmaf(wp[i * CIN + c], xv, acc[i]);
  }

  const int pb = (b * N + n) * 3;
  #pragma unroll
  for (int k = 0; k < 3; ++k) {
    const float wk = wgt[pb + k];
    const int ik = idx[pb + k];
    const float4* zp =
        reinterpret_cast<const float4*>(Z + (b * S + ik) * CO + rg * 32);
    #pragma unroll
    for (int i = 0; i < 8; ++i) {
      float4 zv = zp[i];
      acc[4*i+0] = fmaf(wk, zv.x, acc[4*i+0]);
      acc[4*i+1] = fmaf(wk, zv.y, acc[4*i+1]);
      acc[4*i+2] = fmaf(wk, zv.z, acc[4*i+2]);
      acc[4*i+3] = fmaf(wk, zv.w, acc[4*i+3]);
    }
  }

  float* yp = y + b * CO * N + (rg * 32) * N + n;
  #pragma unroll
  for (int i = 0; i < 32; ++i) yp[i * N] = acc[i];
}

// ---------------------------------------------------------------------------
// K4: per-channel sum / sumsq over (B, N).
// ---------------------------------------------------------------------------
__global__ __launch_bounds__(256) void stats_kernel(
    const float* __restrict__ y, float* __restrict__ stats) {
  const int o = blockIdx.x;
  const int b = blockIdx.y;
  const float4* yp = reinterpret_cast<const float4*>(y + (b * CO + o) * N);
  float s = 0.f, sq = 0.f;
  for (int j = threadIdx.x; j < N / 4; j += 256) {
    float4 v = yp[j];
    s  += v.x + v.y + v.z + v.w;
    sq += v.x * v.x + v.y * v.y + v.z * v.z + v.w * v.w;
  }
  __shared__ float ls[256];
  __shared__ float lq[256];
  ls[threadIdx.x] = s;
  lq[threadIdx.x] = sq;
  __syncthreads();
  for (int st = 128; st > 0; st >>= 1) {
    if (threadIdx.x < (unsigned)st) {
      ls[threadIdx.x] += ls[threadIdx.x + st];
      lq[threadIdx.x] += lq[threadIdx.x + st];
    }
    __syncthreads();
  }
  if (threadIdx.x == 0) {
    atomicAdd(&stats[o], ls[0]);
    atomicAdd(&stats[CO + o], lq[0]);
  }
}

// ---------------------------------------------------------------------------
// K4b: fold BN stats into per-channel scale/shift.
// ---------------------------------------------------------------------------
__global__ void scaleshift_kernel(const float* __restrict__ stats,
                                  const float* __restrict__ gamma,
                                  const float* __restrict__ beta,
                                  float* __restrict__ ss) {
  const int o = threadIdx.x;  // 128 threads
  const float invc = 1.f / (float)(B * N);
  const float m = stats[o] * invc;
  float v = stats[CO + o] * invc - m * m;
  v = fmaxf(v, 0.f);
  const float sc = gamma[o] / sqrtf(v + 1e-5f);
  ss[o] = sc;
  ss[CO + o] = beta[o] - m * sc;
}

// ---------------------------------------------------------------------------
// K5: in-place normalize + LeakyReLU(0.2) on d_out's y region (float4).
// ---------------------------------------------------------------------------
__global__ __launch_bounds__(256) void norm_kernel(float* __restrict__ y,
                                                   const float* __restrict__ ss) {
  const int i = blockIdx.x * 256 + threadIdx.x;  // float4 index
  const int o = (i >> 12) & (CO - 1);            // N/4 = 4096 float4 per (b,o)
  const float sc = ss[o];
  const float sh = ss[CO + o];
  float4* yp = reinterpret_cast<float4*>(y);
  float4 v = yp[i];
  float t;
  t = fmaf(v.x, sc, sh); v.x = fmaxf(t, 0.2f * t);
  t = fmaf(v.y, sc, sh); v.y = fmaxf(t, 0.2f * t);
  t = fmaf(v.z, sc, sh); v.z = fmaxf(t, 0.2f * t);
  t = fmaf(v.w, sc, sh); v.w = fmaxf(t, 0.2f * t);
  yp[i] = v;
}

// ---------------------------------------------------------------------------
extern "C" void kernel_launch(void* const* d_in, const int* in_sizes, int n_in,
                              void* d_out, int out_size, void* d_ws, size_t ws_size,
                              hipStream_t stream) {
  const float* dxyz  = (const float*)d_in[0];
  const float* sxyz  = (const float*)d_in[1];
  const float* ddata = (const float*)d_in[2];
  const float* sdata = (const float*)d_in[3];
  const float* cw    = (const float*)d_in[4];
  const float* gamma = (const float*)d_in[5];
  const float* beta  = (const float*)d_in[6];
  float* out = (float*)d_out;

  char* wsb = (char*)d_ws;
  // Layout (total 14,157,824 B — same proven footprint):
  float*  wgt  = (float*) (wsb);                 // B*N*3 f32   =   786,432 B
  int*    idx  = (int*)   (wsb + 786432);        // B*N*3 i32   =   786,432 B
  double* ckey = (double*)(wsb + 1572864);       // NC*B*N*3 f64 = 6,291,456 B
  // After knn_merge, ckey is dead; Z (8 MB) and Wt (192 KB) alias into it.
  float*  Z    = (float*) (wsb + 1572864);       // B*S*CO f32  = 8,388,608 B
  float*  wt   = (float*) (wsb + 9961472);       // CIN*CO f32  =   196,608 B
  float*  stats= (float*) (wsb + 14155776);      // 256 f32
  float*  ss   = (float*) (wsb + 14156800);      // 256 f32

  hipMemsetAsync(stats, 0, 2 * CO * sizeof(float), stream);

  knn_chunk_kernel<<<dim3(N / (256 * P), NC, B), 256, 0, stream>>>(dxyz, sxyz, ckey);
  knn_merge_kernel<<<dim3(B * N / 256), 256, 0, stream>>>(ckey, dxyz, sxyz, wgt, idx);
  wtrans_kernel   <<<dim3(CO * CIN / 256), 256, 0, stream>>>(cw, wt);
  zproj_kernel    <<<dim3(S / 64, CO / 16, B), 64, 0, stream>>>(sdata, wt, Z);
  ygemm_kernel    <<<dim3(N / 64, B), 256, 0, stream>>>(ddata, cw, Z, wgt, idx, out);
  stats_kernel    <<<dim3(CO, B), 256, 0, stream>>>(out, stats);
  scaleshift_kernel<<<1, 128, 0, stream>>>(stats, gamma, beta, ss);
  norm_kernel     <<<(B * CO * N / 4) / 256, 256, 0, stream>>>(out, ss);

  hipMemcpyAsync(out + (size_t)B * CO * N, dxyz, (size_t)B * 3 * N * sizeof(float),
                 hipMemcpyDeviceToDevice, stream);
}

// Round 7
// 258.752 us; speedup vs baseline: 1.1988x; 1.1988x over previous
//
#include <hip/hip_runtime.h>

// Problem constants (fixed shapes from setup_inputs)
constexpr int B  = 4;
constexpr int N  = 16384;   // dense points
constexpr int S  = 4096;    // sparse points
constexpr int CD = 128;     // dense feature channels
constexpr int CS = 256;     // sparse feature channels
constexpr int CO = 128;     // output channels
constexpr int CIN = CD + CS; // 384

// KNN decomposition (R5-proven occupancy: 1024 blocks, 4096 waves)
constexpr int NC = 8;      // S-chunks
constexpr int CH = S / NC; // 512 sparse points per chunk
constexpr int P  = 2;      // dense points per thread

// Branchless (value,index) top-3 insert. Strict < on values + sequential
// ascending-index arrival order == exact lower-index-wins tie-breaking.
// Flattened selects (each flag consumed immediately) to keep codegen at
// 3 v_cmp + 5 v_cndmask — R2's nested ternaries bloated 3x.
__device__ __forceinline__ void insert3vi(float& d0, float& d1, float& d2,
                                          int& i0, int& i1, int& i2,
                                          float x, int sg) {
  const bool lt2 = x < d2;
  i2 = lt2 ? sg : i2;
  const bool lt1 = x < d1;
  i2 = lt1 ? i1 : i2;
  int i1t = lt1 ? sg : i1;
  const bool lt0 = x < d0;
  i1 = lt0 ? i0 : i1t;
  i0 = lt0 ? sg : i0;
  d2 = fminf(fmaxf(x, d1), d2);
  d1 = __builtin_amdgcn_fmed3f(x, d0, d1);
  d0 = fminf(x, d0);
}

// ---------------------------------------------------------------------------
// K1a: per-chunk top-3, single pass, all-f32 branchless dataflow.
// LDS tile premultiplied to (-2sx,-2sy,-2sz,s2) so the ordering score is
// t = fma(-2sx,dx, fma(-2sy,dy, fma(-2sz,dz, s2))) — 3 fma/pair.
// (R5 paid 40 of its 66 lane-cyc/pair in quarter-rate f64 min/max; R6's
// two-pass branch was taken ~31% of wave-iters. This is flat f32.)
// ---------------------------------------------------------------------------
__global__ __launch_bounds__(256) void knn_chunk_kernel(
    const float* __restrict__ dxyz, const float* __restrict__ sxyz,
    float* __restrict__ cdist, int* __restrict__ cidx) {
  __shared__ float4 sp[CH];   // (-2sx, -2sy, -2sz, s2)
  const int b = blockIdx.z;
  const int c = blockIdx.y;
  const int nbase = blockIdx.x * (256 * P);
  const int t = threadIdx.x;

  const float* sb = sxyz + b * 3 * S + c * CH;
  for (int j = t; j < CH; j += 256) {
    const float sx = sb[j], sy = sb[S + j], sz = sb[2 * S + j];
    sp[j] = make_float4(-2.f * sx, -2.f * sy, -2.f * sz,
                        fmaf(sx, sx, fmaf(sy, sy, sz * sz)));
  }
  __syncthreads();

  float bx[P], by[P], bz[P];
  float d0[P], d1[P], d2[P];
  int   i0[P], i1[P], i2[P];
  #pragma unroll
  for (int p = 0; p < P; ++p) {
    const int n = nbase + p * 256 + t;
    bx[p] = dxyz[b * 3 * N + n];
    by[p] = dxyz[b * 3 * N + N + n];
    bz[p] = dxyz[b * 3 * N + 2 * N + n];
    d0[p] = d1[p] = d2[p] = 1e30f;
    i0[p] = i1[p] = i2[p] = 0;
  }

  #pragma unroll 4
  for (int j = 0; j < CH; ++j) {
    const float4 q = sp[j];                 // wave-uniform LDS broadcast
    const int sg = c * CH + j;              // global sparse index
    #pragma unroll
    for (int p = 0; p < P; ++p) {
      const float x =
          fmaf(q.x, bx[p], fmaf(q.y, by[p], fmaf(q.z, bz[p], q.w)));
      insert3vi(d0[p], d1[p], d2[p], i0[p], i1[p], i2[p], x, sg);
    }
  }

  #pragma unroll
  for (int p = 0; p < P; ++p) {
    const int n = nbase + p * 256 + t;
    const size_t base = (((size_t)c * B + b) * N + n) * 3;
    cdist[base + 0] = d0[p]; cidx[base + 0] = i0[p];
    cdist[base + 1] = d1[p]; cidx[base + 1] = i1[p];
    cdist[base + 2] = d2[p]; cidx[base + 2] = i2[p];
  }
}

// ---------------------------------------------------------------------------
// K1b: merge the NC per-chunk (value,index) triples in ascending chunk order
// (= ascending index order, so strict < keeps lower-index-wins), then compute
// weights in the reference's expanded form max((n2+s2)-2*inner, 0).
// ---------------------------------------------------------------------------
__global__ __launch_bounds__(256) void knn_merge_kernel(
    const float* __restrict__ cdist, const int* __restrict__ cidx,
    const float* __restrict__ dxyz, const float* __restrict__ sxyz,
    float* __restrict__ wgt, int* __restrict__ idx) {
  const int gid = blockIdx.x * 256 + threadIdx.x;  // = b*N + n
  const int b = gid >> 14;                          // N = 16384
  const int n = gid & (N - 1);
  float d0 = 1e30f, d1 = 1e30f, d2 = 1e30f;
  int i0 = 0, i1 = 0, i2 = 0;
  #pragma unroll
  for (int c = 0; c < NC; ++c) {
    const size_t base = ((size_t)c * B * N + gid) * 3;
    #pragma unroll
    for (int k = 0; k < 3; ++k) {
      insert3vi(d0, d1, d2, i0, i1, i2, cdist[base + k], cidx[base + k]);
    }
  }
  int ii[3] = {i0, i1, i2};

  const float bx = dxyz[b * 3 * N + n];
  const float by = dxyz[b * 3 * N + N + n];
  const float bz = dxyz[b * 3 * N + 2 * N + n];
  const float n2 = bx * bx + by * by + bz * bz;
  float w[3];
  #pragma unroll
  for (int k = 0; k < 3; ++k) {
    const float sx = sxyz[b * 3 * S + ii[k]];
    const float sy = sxyz[b * 3 * S + S + ii[k]];
    const float sz = sxyz[b * 3 * S + 2 * S + ii[k]];
    const float s2 = sx * sx + sy * sy + sz * sz;
    const float inner = bx * sx + by * sy + bz * sz;
    const float d = fmaxf((n2 + s2) - 2.f * inner, 0.f);
    w[k] = 1.f / (d + 1e-8f);
  }
  const float inv = 1.f / (w[0] + w[1] + w[2]);
  const size_t base = (size_t)gid * 3;
  wgt[base + 0] = w[0] * inv;
  wgt[base + 1] = w[1] * inv;
  wgt[base + 2] = w[2] * inv;
  idx[base + 0] = ii[0];
  idx[base + 1] = ii[1];
  idx[base + 2] = ii[2];
}

// ---------------------------------------------------------------------------
// K1c: transpose conv_w -> Wt[c][o] (o contiguous) for zproj's uniform loads.
// ---------------------------------------------------------------------------
__global__ __launch_bounds__(256) void wtrans_kernel(
    const float* __restrict__ cw, float* __restrict__ wt) {
  const int i = blockIdx.x * 256 + threadIdx.x;  // over CO*CIN, coalesced read
  const int o = i / CIN;
  const int c = i - o * CIN;
  wt[c * CO + o] = cw[i];
}

// ---------------------------------------------------------------------------
// K2: Z[b, s, o] = sum_c Ws[o, c] * sparse_data[b, c, s]   (o-contiguous!)
// 1-wave blocks, 16 channels/thread, grid (S/64, CO/16, B) = 2048 waves.
// ---------------------------------------------------------------------------
__global__ __launch_bounds__(64) void zproj_kernel(
    const float* __restrict__ sdata, const float* __restrict__ wt,
    float* __restrict__ Z) {
  const int b = blockIdx.z;
  const int og = blockIdx.y;                      // 8 groups of 16 channels
  const int s = blockIdx.x * 64 + threadIdx.x;
  const float* __restrict__ xp = sdata + b * CS * S + s;
  const float* __restrict__ wp = wt + CD * CO + og * 16;  // Wt[CD+c][og*16..]

  float acc[16];
  #pragma unroll
  for (int i = 0; i < 16; ++i) acc[i] = 0.f;

  #pragma unroll 4
  for (int c = 0; c < CS; ++c) {
    const float xv = xp[c * S];        // coalesced across the wave
    #pragma unroll
    for (int i = 0; i < 16; ++i)
      acc[i] = fmaf(wp[c * CO + i], xv, acc[i]);  // uniform 64B s_load
  }

  float4* zp = reinterpret_cast<float4*>(Z + (b * S + s) * CO + og * 16);
  #pragma unroll
  for (int i = 0; i < 4; ++i)
    zp[i] = make_float4(acc[4*i+0], acc[4*i+1], acc[4*i+2], acc[4*i+3]);
}

// ---------------------------------------------------------------------------
// K3: y[b, o, n] = sum_c Wd[o,c]*dense_data[b,c,n] + sum_k w_k * Z[b,idx_k,o]
// (no fused stats — R3 showed that fusion forces an accumulator spill)
// ---------------------------------------------------------------------------
__global__ __launch_bounds__(256) void ygemm_kernel(
    const float* __restrict__ ddata, const float* __restrict__ cw,
    const float* __restrict__ Z, const float* __restrict__ wgt,
    const int* __restrict__ idx, float* __restrict__ y) {
  const int b = blockIdx.y;
  const int n = blockIdx.x * 64 + (threadIdx.x & 63);
  const int rg = __builtin_amdgcn_readfirstlane(threadIdx.x >> 6);
  const float* __restrict__ xp = ddata + b * CD * N + n;
  const float* __restrict__ wp = cw + rg * 32 * CIN;  // Wd columns

  float acc[32];
  #pragma unroll
  for (int i = 0; i < 32; ++i) acc[i] = 0.f;

  #pragma unroll 4
  for (int c = 0; c < CD; ++c) {
    const float xv = xp[c * N];
    #pragma unroll
    for (int i = 0; i < 32; ++i)
      acc[i] = fmaf(wp[i * CIN + c], xv, acc[i]);
  }

  const int pb = (b * N + n) * 3;
  #pragma unroll
  for (int k = 0; k < 3; ++k) {
    const float wk = wgt[pb + k];
    const int ik = idx[pb + k];
    const float4* zp =
        reinterpret_cast<const float4*>(Z + (b * S + ik) * CO + rg * 32);
    #pragma unroll
    for (int i = 0; i < 8; ++i) {
      float4 zv = zp[i];
      acc[4*i+0] = fmaf(wk, zv.x, acc[4*i+0]);
      acc[4*i+1] = fmaf(wk, zv.y, acc[4*i+1]);
      acc[4*i+2] = fmaf(wk, zv.z, acc[4*i+2]);
      acc[4*i+3] = fmaf(wk, zv.w, acc[4*i+3]);
    }
  }

  float* yp = y + b * CO * N + (rg * 32) * N + n;
  #pragma unroll
  for (int i = 0; i < 32; ++i) yp[i * N] = acc[i];
}

// ---------------------------------------------------------------------------
// K4: per-channel sum / sumsq over (B, N).
// ---------------------------------------------------------------------------
__global__ __launch_bounds__(256) void stats_kernel(
    const float* __restrict__ y, float* __restrict__ stats) {
  const int o = blockIdx.x;
  const int b = blockIdx.y;
  const float4* yp = reinterpret_cast<const float4*>(y + (b * CO + o) * N);
  float s = 0.f, sq = 0.f;
  for (int j = threadIdx.x; j < N / 4; j += 256) {
    float4 v = yp[j];
    s  += v.x + v.y + v.z + v.w;
    sq += v.x * v.x + v.y * v.y + v.z * v.z + v.w * v.w;
  }
  __shared__ float ls[256];
  __shared__ float lq[256];
  ls[threadIdx.x] = s;
  lq[threadIdx.x] = sq;
  __syncthreads();
  for (int st = 128; st > 0; st >>= 1) {
    if (threadIdx.x < (unsigned)st) {
      ls[threadIdx.x] += ls[threadIdx.x + st];
      lq[threadIdx.x] += lq[threadIdx.x + st];
    }
    __syncthreads();
  }
  if (threadIdx.x == 0) {
    atomicAdd(&stats[o], ls[0]);
    atomicAdd(&stats[CO + o], lq[0]);
  }
}

// ---------------------------------------------------------------------------
// K4b: fold BN stats into per-channel scale/shift.
// ---------------------------------------------------------------------------
__global__ void scaleshift_kernel(const float* __restrict__ stats,
                                  const float* __restrict__ gamma,
                                  const float* __restrict__ beta,
                                  float* __restrict__ ss) {
  const int o = threadIdx.x;  // 128 threads
  const float invc = 1.f / (float)(B * N);
  const float m = stats[o] * invc;
  float v = stats[CO + o] * invc - m * m;
  v = fmaxf(v, 0.f);
  const float sc = gamma[o] / sqrtf(v + 1e-5f);
  ss[o] = sc;
  ss[CO + o] = beta[o] - m * sc;
}

// ---------------------------------------------------------------------------
// K5: in-place normalize + LeakyReLU(0.2) on d_out's y region (float4).
// ---------------------------------------------------------------------------
__global__ __launch_bounds__(256) void norm_kernel(float* __restrict__ y,
                                                   const float* __restrict__ ss) {
  const int i = blockIdx.x * 256 + threadIdx.x;  // float4 index
  const int o = (i >> 12) & (CO - 1);            // N/4 = 4096 float4 per (b,o)
  const float sc = ss[o];
  const float sh = ss[CO + o];
  float4* yp = reinterpret_cast<float4*>(y);
  float4 v = yp[i];
  float t;
  t = fmaf(v.x, sc, sh); v.x = fmaxf(t, 0.2f * t);
  t = fmaf(v.y, sc, sh); v.y = fmaxf(t, 0.2f * t);
  t = fmaf(v.z, sc, sh); v.z = fmaxf(t, 0.2f * t);
  t = fmaf(v.w, sc, sh); v.w = fmaxf(t, 0.2f * t);
  yp[i] = v;
}

// ---------------------------------------------------------------------------
extern "C" void kernel_launch(void* const* d_in, const int* in_sizes, int n_in,
                              void* d_out, int out_size, void* d_ws, size_t ws_size,
                              hipStream_t stream) {
  const float* dxyz  = (const float*)d_in[0];
  const float* sxyz  = (const float*)d_in[1];
  const float* ddata = (const float*)d_in[2];
  const float* sdata = (const float*)d_in[3];
  const float* cw    = (const float*)d_in[4];
  const float* gamma = (const float*)d_in[5];
  const float* beta  = (const float*)d_in[6];
  float* out = (float*)d_out;

  char* wsb = (char*)d_ws;
  // Layout (total 14,157,824 B — same proven footprint):
  float*  wgt  = (float*) (wsb);                 // B*N*3 f32   =   786,432 B
  int*    idx  = (int*)   (wsb + 786432);        // B*N*3 i32   =   786,432 B
  float*  cdist= (float*) (wsb + 1572864);       // NC*B*N*3 f32 = 6,291,456 B
  int*    cidx = (int*)   (wsb + 7864320);       // NC*B*N*3 i32 = 6,291,456 B
  // After knn_merge, cdist/cidx are dead; Z and Wt alias into that region.
  float*  Z    = (float*) (wsb + 1572864);       // B*S*CO f32  = 8,388,608 B
  float*  wt   = (float*) (wsb + 9961472);       // CIN*CO f32  =   196,608 B
  float*  stats= (float*) (wsb + 14155776);      // 256 f32
  float*  ss   = (float*) (wsb + 14156800);      // 256 f32

  hipMemsetAsync(stats, 0, 2 * CO * sizeof(float), stream);

  knn_chunk_kernel<<<dim3(N / (256 * P), NC, B), 256, 0, stream>>>(dxyz, sxyz, cdist, cidx);
  knn_merge_kernel<<<dim3(B * N / 256), 256, 0, stream>>>(cdist, cidx, dxyz, sxyz, wgt, idx);
  wtrans_kernel   <<<dim3(CO * CIN / 256), 256, 0, stream>>>(cw, wt);
  zproj_kernel    <<<dim3(S / 64, CO / 16, B), 64, 0, stream>>>(sdata, wt, Z);
  ygemm_kernel    <<<dim3(N / 64, B), 256, 0, stream>>>(ddata, cw, Z, wgt, idx, out);
  stats_kernel    <<<dim3(CO, B), 256, 0, stream>>>(out, stats);
  scaleshift_kernel<<<1, 128, 0, stream>>>(stats, gamma, beta, ss);
  norm_kernel     <<<(B * CO * N / 4) / 256, 256, 0, stream>>>(out, ss);

  hipMemcpyAsync(out + (size_t)B * CO * N, dxyz, (size_t)B * 3 * N * sizeof(float),
                 hipMemcpyDeviceToDevice, stream);
}